// Round 10
// baseline (501.292 us; speedup 1.0000x reference)
//
#include <hip/hip_runtime.h>
#include <hip/hip_bf16.h>

#define C 192
#define NHh 6
#define NT 49
#define IMG 64
#define WSZ 7

#define XS2 200   // xn/ao LDS stride (bf16)
#define QKS 392
#define VTS 72
#define PLS 72
#define X3S 200   // conv_mlp4 row stride (bf16)

typedef __attribute__((ext_vector_type(8))) short bf16x8;
typedef __attribute__((ext_vector_type(4))) float f32x4;

__device__ __forceinline__ float bf2f(unsigned short u) {
    union { unsigned int i; float f; } v; v.i = ((unsigned int)u) << 16; return v.f;
}
__device__ __forceinline__ unsigned short f2bf(float f) {
    __hip_bfloat16 h = __float2bfloat16(f);
    return *(unsigned short*)&h;
}
__device__ __forceinline__ float gelu_f(float v) {
    return 0.5f * v * (1.f + erff(v * 0.70710678118654752f));
}

// ---------------- prep A: LDS-tiled transposes (coalesced read AND write) ----------------
__global__ __launch_bounds__(256) void prep_kernel(
    const float* __restrict__ fc1_w, const float* __restrict__ fc2_w,
    const float* __restrict__ qkv_w, const float* __restrict__ proj_w,
    const float* __restrict__ biases, int noff, const int* __restrict__ bidx,
    const float* __restrict__ bn_g, const float* __restrict__ bn_b,
    const float* __restrict__ bn_m, const float* __restrict__ bn_v,
    const float* __restrict__ conv_w,
    unsigned short* __restrict__ wfc1t, unsigned short* __restrict__ wfc2t,
    unsigned short* __restrict__ wqkvt, unsigned short* __restrict__ wprojt,
    float* __restrict__ biasfp, float* __restrict__ bnsc, float* __restrict__ bnsh,
    float* __restrict__ convwt)
{
    __shared__ unsigned short tbuf[64 * 68];
    const int bid = blockIdx.x, tid = threadIdx.x;

    if (bid < 108) {
        const float* src; unsigned short* dst; int K, N, tk, tn;
        if (bid < 36)      { src = fc1_w;  dst = wfc1t;  K = 192; N = 768; tk = bid/12;      tn = bid%12; }
        else if (bid < 72) { src = fc2_w;  dst = wfc2t;  K = 768; N = 192; tk = (bid-36)/3;  tn = (bid-36)%3; }
        else if (bid < 99) { src = qkv_w;  dst = wqkvt;  K = 192; N = 576; tk = (bid-72)/9;  tn = (bid-72)%9; }
        else               { src = proj_w; dst = wprojt; K = 192; N = 192; tk = (bid-99)/3;  tn = (bid-99)%3; }
        for (int i = tid; i < 1024; i += 256) {
            int r = i >> 4, c = (i & 15) * 4;
            float4 v = *(const float4*)(src + (size_t)(tk*64 + r) * N + tn*64 + c);
            ushort4 s; s.x = f2bf(v.x); s.y = f2bf(v.y); s.z = f2bf(v.z); s.w = f2bf(v.w);
            *(ushort4*)&tbuf[r*68 + c] = s;
        }
        __syncthreads();
        for (int i = tid; i < 1024; i += 256) {
            int n = i >> 4, k = (i & 15) * 4;
            ushort4 o;
            o.x = tbuf[(k+0)*68 + n];
            o.y = tbuf[(k+1)*68 + n];
            o.z = tbuf[(k+2)*68 + n];
            o.w = tbuf[(k+3)*68 + n];
            *(ushort4*)(dst + (size_t)(tn*64 + n) * K + tk*64 + k) = o;
        }
    } else if (bid < 204) {
        int j = (bid - 108) * 256 + tid;
        if (j < 24576) {
            int h = j >> 12, rem = j & 4095;
            int q = rem >> 6, k = rem & 63;
            biasfp[j] = (q < NT && k < NT) ? biases[h * noff + bidx[q * NT + k]] : -1.0e30f;
        }
    } else {
        for (int it = tid; it < 1920; it += 256) {
            if (it < 192) {
                float sc = bn_g[it] * rsqrtf(bn_v[it] + 1e-5f);
                bnsc[it] = sc;
                bnsh[it] = bn_b[it] - bn_m[it] * sc;
            } else {
                int idx = it - 192;
                int tap = idx / 192, c = idx - tap * 192;
                convwt[tap * 192 + c] = conv_w[c * 9 + tap];
            }
        }
    }
}

// ---------------- K1 (MFMA, 8 waves): LN1 -> qkv -> windowed attn -> proj + residual ----------------
__global__ __launch_bounds__(512) void attn_win_mfma(
    const float* __restrict__ x,
    const float* __restrict__ ln1_w, const float* __restrict__ ln1_b,
    const unsigned short* __restrict__ wqkvt, const float* __restrict__ qkv_b,
    const float* __restrict__ biasfp,
    const unsigned short* __restrict__ wprojt, const float* __restrict__ proj_b,
    unsigned short* __restrict__ x2)
{
    extern __shared__ char smem[];
    unsigned short* xn = (unsigned short*)smem;               // [64][XS2]  25600 B (reused as ao)
    unsigned short* qk = (unsigned short*)(smem + 25600);     // [64][QKS]  50176 B
    unsigned short* vt = (unsigned short*)(smem + 75776);     // [6*32][VTS] 27648 B
    unsigned short* pl = (unsigned short*)(smem + 103424);    // [8][16][PLS] 18432 B
    float* stats = (float*)(smem + 121856);                   // [64][2] 512 B

    const int tid = threadIdx.x;
    const int blk = blockIdx.x;
    const int b  = blk / 100;
    const int wi = (blk / 10) % 10;
    const int wj = blk % 10;
    const size_t base = (size_t)b * 4096;
    const int wid = tid >> 6, lane = tid & 63, lr = lane & 15, lg = lane >> 4;

    for (int idx = tid; idx < 64*48; idx += 512) {
        int t = idx / 48, c0 = (idx - t*48) * 4;
        ushort4 sv; sv.x = 0; sv.y = 0; sv.z = 0; sv.w = 0;
        if (t < NT) {
            int gh = wi*WSZ + t/WSZ, gw = wj*WSZ + t%WSZ;
            if (gh < IMG && gw < IMG) {
                float4 v = *(const float4*)(x + (base + (size_t)(gh*IMG + gw))*C + c0);
                sv.x = f2bf(v.x); sv.y = f2bf(v.y); sv.z = f2bf(v.z); sv.w = f2bf(v.w);
            }
        }
        *(ushort4*)&xn[t*XS2 + c0] = sv;
    }
    __syncthreads();

    {
        int lt = tid >> 3, sl = tid & 7;
        float s = 0.f, s2 = 0.f;
        for (int c = sl; c < C; c += 8) {
            float v = bf2f(xn[lt*XS2 + c]);
            s += v; s2 += v*v;
        }
        #pragma unroll
        for (int msk = 1; msk < 8; msk <<= 1) {
            s  += __shfl_xor(s,  msk, 64);
            s2 += __shfl_xor(s2, msk, 64);
        }
        if (sl == 0) {
            float m = s * (1.f/C), var = s2 * (1.f/C) - m*m;
            stats[2*lt]   = m;
            stats[2*lt+1] = rsqrtf(var + 1e-5f);
        }
    }
    __syncthreads();

    for (int idx = tid; idx < 64*48; idx += 512) {
        int t = idx / 48, c0 = (idx - t*48) * 4;
        float mm = stats[2*t], rr = stats[2*t+1];
        ushort4 sv = *(ushort4*)&xn[t*XS2 + c0];
        sv.x = f2bf((bf2f(sv.x) - mm) * rr * ln1_w[c0+0] + ln1_b[c0+0]);
        sv.y = f2bf((bf2f(sv.y) - mm) * rr * ln1_w[c0+1] + ln1_b[c0+1]);
        sv.z = f2bf((bf2f(sv.z) - mm) * rr * ln1_w[c0+2] + ln1_b[c0+2]);
        sv.w = f2bf((bf2f(sv.w) - mm) * rr * ln1_w[c0+3] + ln1_b[c0+3]);
        *(ushort4*)&xn[t*XS2 + c0] = sv;
    }
    __syncthreads();

    for (int nt = wid; nt < 36; nt += 8) {
        const int ncol = nt*16 + lr;
        f32x4 acc0 = {0.f,0.f,0.f,0.f}, acc1 = {0.f,0.f,0.f,0.f};
        f32x4 acc2 = {0.f,0.f,0.f,0.f}, acc3 = {0.f,0.f,0.f,0.f};
        const unsigned short* wp = wqkvt + ncol*192 + lg*8;
        #pragma unroll
        for (int ks = 0; ks < 6; ++ks) {
            bf16x8 bfr = *(const bf16x8*)(wp + ks*32);
            bf16x8 a0 = *(const bf16x8*)(xn + (0*16+lr)*XS2 + ks*32 + lg*8);
            bf16x8 a1 = *(const bf16x8*)(xn + (1*16+lr)*XS2 + ks*32 + lg*8);
            bf16x8 a2 = *(const bf16x8*)(xn + (2*16+lr)*XS2 + ks*32 + lg*8);
            bf16x8 a3 = *(const bf16x8*)(xn + (3*16+lr)*XS2 + ks*32 + lg*8);
            acc0 = __builtin_amdgcn_mfma_f32_16x16x32_bf16(a0, bfr, acc0, 0, 0, 0);
            acc1 = __builtin_amdgcn_mfma_f32_16x16x32_bf16(a1, bfr, acc1, 0, 0, 0);
            acc2 = __builtin_amdgcn_mfma_f32_16x16x32_bf16(a2, bfr, acc2, 0, 0, 0);
            acc3 = __builtin_amdgcn_mfma_f32_16x16x32_bf16(a3, bfr, acc3, 0, 0, 0);
        }
        float bias = qkv_b[ncol];
        const int h = ncol / 96, wo = ncol - h*96;
        #pragma unroll
        for (int mt = 0; mt < 4; ++mt) {
            f32x4 av = (mt==0) ? acc0 : (mt==1) ? acc1 : (mt==2) ? acc2 : acc3;
            #pragma unroll
            for (int r = 0; r < 4; ++r) {
                int tok = mt*16 + lg*4 + r;
                unsigned short v = f2bf(av[r] + bias);
                if (wo < 64) qk[tok*QKS + h*64 + wo] = v;
                else         vt[(h*32 + (wo-64))*VTS + tok] = v;
            }
        }
    }
    __syncthreads();

    unsigned short* ao = xn;
    for (int u = wid; u < 24; u += 8) {
        const int h = u >> 2, nq = u & 3;
        const int qg = nq*16 + lr;
        f32x4 s0 = {0.f,0.f,0.f,0.f}, s1 = {0.f,0.f,0.f,0.f};
        f32x4 s2 = {0.f,0.f,0.f,0.f}, s3 = {0.f,0.f,0.f,0.f};
        bf16x8 qf = *(const bf16x8*)(qk + qg*QKS + h*64 + lg*8);
        bf16x8 k0 = *(const bf16x8*)(qk + (0*16+lr)*QKS + h*64 + 32 + lg*8);
        bf16x8 k1 = *(const bf16x8*)(qk + (1*16+lr)*QKS + h*64 + 32 + lg*8);
        bf16x8 k2 = *(const bf16x8*)(qk + (2*16+lr)*QKS + h*64 + 32 + lg*8);
        bf16x8 k3 = *(const bf16x8*)(qk + (3*16+lr)*QKS + h*64 + 32 + lg*8);
        s0 = __builtin_amdgcn_mfma_f32_16x16x32_bf16(k0, qf, s0, 0, 0, 0);
        s1 = __builtin_amdgcn_mfma_f32_16x16x32_bf16(k1, qf, s1, 0, 0, 0);
        s2 = __builtin_amdgcn_mfma_f32_16x16x32_bf16(k2, qf, s2, 0, 0, 0);
        s3 = __builtin_amdgcn_mfma_f32_16x16x32_bf16(k3, qf, s3, 0, 0, 0);
        const float* bp = biasfp + (size_t)(h*64 + qg)*64 + lg*4;
        float sv[4][4];
        float mx = -3.0e38f;
        #pragma unroll
        for (int mk = 0; mk < 4; ++mk) {
            f32x4 sa = (mk==0) ? s0 : (mk==1) ? s1 : (mk==2) ? s2 : s3;
            float4 b4 = *(const float4*)(bp + mk*16);
            sv[mk][0] = sa[0] * 0.17677669529663687f + b4.x;
            sv[mk][1] = sa[1] * 0.17677669529663687f + b4.y;
            sv[mk][2] = sa[2] * 0.17677669529663687f + b4.z;
            sv[mk][3] = sa[3] * 0.17677669529663687f + b4.w;
            #pragma unroll
            for (int r = 0; r < 4; ++r) mx = fmaxf(mx, sv[mk][r]);
        }
        mx = fmaxf(mx, __shfl_xor(mx, 16, 64));
        mx = fmaxf(mx, __shfl_xor(mx, 32, 64));
        float sum = 0.f;
        #pragma unroll
        for (int mk = 0; mk < 4; ++mk)
            #pragma unroll
            for (int r = 0; r < 4; ++r) { sv[mk][r] = __expf(sv[mk][r] - mx); sum += sv[mk][r]; }
        sum += __shfl_xor(sum, 16, 64);
        sum += __shfl_xor(sum, 32, 64);
        float inv = 1.f / sum;
        unsigned short* pw = pl + (wid*16 + lr)*PLS;
        #pragma unroll
        for (int mk = 0; mk < 4; ++mk)
            #pragma unroll
            for (int r = 0; r < 4; ++r) pw[mk*16 + lg*4 + r] = f2bf(sv[mk][r] * inv);
        #pragma unroll
        for (int dt = 0; dt < 2; ++dt) {
            f32x4 oa = {0.f,0.f,0.f,0.f};
            #pragma unroll
            for (int kk = 0; kk < 2; ++kk) {
                bf16x8 vf = *(const bf16x8*)(vt + (h*32 + dt*16 + lr)*VTS + kk*32 + lg*8);
                bf16x8 pf = *(const bf16x8*)(pl + (wid*16 + lr)*PLS + kk*32 + lg*8);
                oa = __builtin_amdgcn_mfma_f32_16x16x32_bf16(vf, pf, oa, 0, 0, 0);
            }
            #pragma unroll
            for (int r = 0; r < 4; ++r)
                ao[(nq*16 + lr)*XS2 + h*32 + dt*16 + lg*4 + r] = f2bf(oa[r]);
        }
    }
    __syncthreads();

    for (int nt = wid; nt < 12; nt += 8) {
        const int ncol = nt*16 + lr;
        f32x4 acc0 = {0.f,0.f,0.f,0.f}, acc1 = {0.f,0.f,0.f,0.f};
        f32x4 acc2 = {0.f,0.f,0.f,0.f}, acc3 = {0.f,0.f,0.f,0.f};
        const unsigned short* wp = wprojt + ncol*192 + lg*8;
        #pragma unroll
        for (int ks = 0; ks < 6; ++ks) {
            bf16x8 bfr = *(const bf16x8*)(wp + ks*32);
            bf16x8 a0 = *(const bf16x8*)(ao + (0*16+lr)*XS2 + ks*32 + lg*8);
            bf16x8 a1 = *(const bf16x8*)(ao + (1*16+lr)*XS2 + ks*32 + lg*8);
            bf16x8 a2 = *(const bf16x8*)(ao + (2*16+lr)*XS2 + ks*32 + lg*8);
            bf16x8 a3 = *(const bf16x8*)(ao + (3*16+lr)*XS2 + ks*32 + lg*8);
            acc0 = __builtin_amdgcn_mfma_f32_16x16x32_bf16(a0, bfr, acc0, 0, 0, 0);
            acc1 = __builtin_amdgcn_mfma_f32_16x16x32_bf16(a1, bfr, acc1, 0, 0, 0);
            acc2 = __builtin_amdgcn_mfma_f32_16x16x32_bf16(a2, bfr, acc2, 0, 0, 0);
            acc3 = __builtin_amdgcn_mfma_f32_16x16x32_bf16(a3, bfr, acc3, 0, 0, 0);
        }
        float bias = proj_b[ncol];
        #pragma unroll
        for (int mt = 0; mt < 4; ++mt) {
            f32x4 av = (mt==0) ? acc0 : (mt==1) ? acc1 : (mt==2) ? acc2 : acc3;
            #pragma unroll
            for (int r = 0; r < 4; ++r) {
                int tok = mt*16 + lg*4 + r;
                if (tok >= NT) continue;
                int gh = wi*WSZ + tok/WSZ, gw = wj*WSZ + tok%WSZ;
                if (gh >= IMG || gw >= IMG) continue;
                size_t g = (base + (size_t)(gh*IMG + gw))*C + ncol;
                x2[g] = f2bf(av[r] + bias + x[g]);
            }
        }
    }
}

// ---- fc1-chunk produce / fc2-chunk consume helpers (chunk = 192 hidden cols) ----
__device__ __forceinline__ f32x4 mfma16(bf16x8 a, bf16x8 b, f32x4 c) {
    return __builtin_amdgcn_mfma_f32_16x16x32_bf16(a, b, c, 0, 0, 0);
}

__device__ __forceinline__ void mlp_produce(
    int ch, unsigned short* buf, const unsigned short* xnl,
    const unsigned short* __restrict__ wfc1t, const float* __restrict__ fc1_b,
    int wid, int lr, int lk)
{
    bf16x8 xa0[6], xa1[6];
    #pragma unroll
    for (int ks = 0; ks < 6; ++ks) {
        xa0[ks] = *(const bf16x8*)(xnl + lr*X3S + ks*32 + lk*8);
        xa1[ks] = *(const bf16x8*)(xnl + (16+lr)*X3S + ks*32 + lk*8);
    }
    #pragma unroll
    for (int t = 0; t < 3; ++t) {
        const int nl = (wid*3 + t)*16 + lr;
        const int ncol = ch*192 + nl;
        f32x4 a0 = {0.f,0.f,0.f,0.f}, a1 = {0.f,0.f,0.f,0.f};
        const unsigned short* wp = wfc1t + (size_t)ncol*192 + lk*8;
        #pragma unroll
        for (int ks = 0; ks < 6; ++ks) {
            bf16x8 bfr = *(const bf16x8*)(wp + ks*32);
            a0 = mfma16(xa0[ks], bfr, a0);
            a1 = mfma16(xa1[ks], bfr, a1);
        }
        float bias = fc1_b[ncol];
        #pragma unroll
        for (int r = 0; r < 4; ++r) {
            int row0 = lk*4 + r;
            buf[row0*X3S + nl]      = f2bf(gelu_f(a0[r] + bias));
            buf[(row0+16)*X3S + nl] = f2bf(gelu_f(a1[r] + bias));
        }
    }
}

__device__ __forceinline__ void mlp_consume(
    int ch, const unsigned short* buf,
    const unsigned short* __restrict__ wfc2t,
    f32x4* acc0, f32x4* acc1, int nb2, int lr, int lk)
{
    #pragma unroll
    for (int ks = 0; ks < 6; ++ks) {
        bf16x8 af0 = *(const bf16x8*)(buf + lr*X3S + ks*32 + lk*8);
        bf16x8 af1 = *(const bf16x8*)(buf + (16+lr)*X3S + ks*32 + lk*8);
        #pragma unroll
        for (int n = 0; n < 3; ++n) {
            bf16x8 b = *(const bf16x8*)(wfc2t + (size_t)(nb2 + n*16 + lr)*768 + ch*192 + ks*32 + lk*8);
            acc0[n] = mfma16(af0, b, acc0[n]);
            acc1[n] = mfma16(af1, b, acc1[n]);
        }
    }
}

// -------- K2 (fused, MFMA, 6 blocks/CU): conv3x3+BN -> out(global f32) + in-wave LN2 ->
//          xnl LDS ; fc1/fc2 single-buffer chunk loop ; epilogue + residual(out) -> out --------
__global__ __launch_bounds__(256, 6) void conv_mlp4(
    const unsigned short* __restrict__ x2,
    const float* __restrict__ convwt,
    const float* __restrict__ bnsc, const float* __restrict__ bnsh,
    const float* __restrict__ ln2_w, const float* __restrict__ ln2_b,
    const unsigned short* __restrict__ wfc1t, const float* __restrict__ fc1_b,
    const unsigned short* __restrict__ wfc2t, const float* __restrict__ fc2_b,
    float* out)
{
    extern __shared__ char smem[];
    unsigned short* xnl = (unsigned short*)smem;             // [32][X3S] 12800
    unsigned short* h1  = (unsigned short*)(smem + 12800);   // [32][X3S] 12800 (single chunk buf)

    const int tid  = threadIdx.x;
    const int base = blockIdx.x * 32;
    const int b    = base >> 12;
    const int n0   = base & 4095;
    const int hh   = n0 >> 6;
    const int w0v  = n0 & 63;
    const size_t ibase = (size_t)b * 4096;

    // P0: conv+BN (8 lanes/token) -> x3 regs -> global out + in-wave LN2 -> xnl LDS
    {
        const int lt = tid >> 3, sl = tid & 7;
        const int ww = w0v + lt;
        float4 xv[6];
        #pragma unroll
        for (int j = 0; j < 6; ++j) { xv[j].x = 0.f; xv[j].y = 0.f; xv[j].z = 0.f; xv[j].w = 0.f; }
        #pragma unroll
        for (int kh = -1; kh <= 1; ++kh) {
            int h2 = hh + kh;
            if (h2 < 0 || h2 >= IMG) continue;
            #pragma unroll
            for (int kw = -1; kw <= 1; ++kw) {
                int w2 = ww + kw;
                if (w2 < 0 || w2 >= IMG) continue;
                const unsigned short* src = x2 + (ibase + (size_t)(h2*IMG + w2))*C;
                const float* wt = convwt + ((kh+1)*3 + (kw+1)) * 192;
                #pragma unroll
                for (int j = 0; j < 6; ++j) {
                    int c0 = (sl + 8*j) * 4;
                    ushort4 v = *(const ushort4*)(src + c0);
                    float4 w = *(const float4*)(wt + c0);
                    xv[j].x += bf2f(v.x) * w.x;
                    xv[j].y += bf2f(v.y) * w.y;
                    xv[j].z += bf2f(v.z) * w.z;
                    xv[j].w += bf2f(v.w) * w.w;
                }
            }
        }
        float s = 0.f, s2 = 0.f;
        #pragma unroll
        for (int j = 0; j < 6; ++j) {
            int c0 = (sl + 8*j) * 4;
            float4 sc = *(const float4*)(bnsc + c0);
            float4 sh = *(const float4*)(bnsh + c0);
            xv[j].x = xv[j].x * sc.x + sh.x;
            xv[j].y = xv[j].y * sc.y + sh.y;
            xv[j].z = xv[j].z * sc.z + sh.z;
            xv[j].w = xv[j].w * sc.w + sh.w;
            *(float4*)(out + ((size_t)base + lt)*C + c0) = xv[j];   // x3 -> residual store
            s  += xv[j].x + xv[j].y + xv[j].z + xv[j].w;
            s2 += xv[j].x*xv[j].x + xv[j].y*xv[j].y + xv[j].z*xv[j].z + xv[j].w*xv[j].w;
        }
        #pragma unroll
        for (int msk = 1; msk < 8; msk <<= 1) {
            s  += __shfl_xor(s,  msk, 64);
            s2 += __shfl_xor(s2, msk, 64);
        }
        float m = s * (1.f/C), var = s2 * (1.f/C) - m*m;
        float rs = rsqrtf(var + 1e-5f);
        #pragma unroll
        for (int j = 0; j < 6; ++j) {
            int c0 = (sl + 8*j) * 4;
            float4 lw = *(const float4*)(ln2_w + c0);
            float4 lb = *(const float4*)(ln2_b + c0);
            ushort4 sv;
            sv.x = f2bf((xv[j].x - m) * rs * lw.x + lb.x);
            sv.y = f2bf((xv[j].y - m) * rs * lw.y + lb.y);
            sv.z = f2bf((xv[j].z - m) * rs * lw.z + lb.z);
            sv.w = f2bf((xv[j].w - m) * rs * lw.w + lb.w);
            *(ushort4*)&xnl[lt*X3S + c0] = sv;
        }
    }
    __syncthreads();

    const int wid = tid >> 6, l = tid & 63, lr = l & 15, lk = l >> 4;
    const int nb2 = wid * 48;

    f32x4 acc0[3] = {{0.f,0.f,0.f,0.f},{0.f,0.f,0.f,0.f},{0.f,0.f,0.f,0.f}};
    f32x4 acc1[3] = {{0.f,0.f,0.f,0.f},{0.f,0.f,0.f,0.f},{0.f,0.f,0.f,0.f}};

    // single-buffer chunk loop: produce -> bar -> consume -> bar
    #pragma unroll 1
    for (int ch = 0; ch < 4; ++ch) {
        mlp_produce(ch, h1, xnl, wfc1t, fc1_b, wid, lr, lk);
        __syncthreads();
        mlp_consume(ch, h1, wfc2t, acc0, acc1, nb2, lr, lk);
        if (ch < 3) __syncthreads();
    }

    // epilogue: +bias +residual (x3 re-read from global, L2-hot) -> out
    #pragma unroll
    for (int n = 0; n < 3; ++n) {
        int col = nb2 + n*16 + lr;
        float bias = fc2_b[col];
        #pragma unroll
        for (int r = 0; r < 4; ++r) {
            int row0 = lk*4 + r;
            size_t g0 = (size_t)(base + row0) * C + col;
            size_t g1 = (size_t)(base + row0 + 16) * C + col;
            float v0 = acc0[n][r] + bias + out[g0];
            float v1 = acc1[n][r] + bias + out[g1];
            out[g0] = v0;
            out[g1] = v1;
        }
    }
}

extern "C" void kernel_launch(void* const* d_in, const int* in_sizes, int n_in,
                              void* d_out, int out_size, void* d_ws, size_t ws_size,
                              hipStream_t stream)
{
    const float* x      = (const float*)d_in[0];
    const float* ln1_w  = (const float*)d_in[1];
    const float* ln1_b  = (const float*)d_in[2];
    const float* qkv_w  = (const float*)d_in[3];
    const float* qkv_b  = (const float*)d_in[4];
    const float* biases = (const float*)d_in[5];
    const float* proj_w = (const float*)d_in[6];
    const float* proj_b = (const float*)d_in[7];
    const float* conv_w = (const float*)d_in[8];
    const float* bn_g   = (const float*)d_in[9];
    const float* bn_b   = (const float*)d_in[10];
    const float* bn_m   = (const float*)d_in[11];
    const float* bn_v   = (const float*)d_in[12];
    const float* ln2_w  = (const float*)d_in[13];
    const float* ln2_b  = (const float*)d_in[14];
    const float* fc1_w  = (const float*)d_in[15];
    const float* fc1_b  = (const float*)d_in[16];
    const float* fc2_w  = (const float*)d_in[17];
    const float* fc2_b  = (const float*)d_in[18];
    const int* bidx     = (const int*)d_in[19];

    char* ws = (char*)d_ws;
    unsigned short* x2    = (unsigned short*)ws;                  // 25,165,824 B
    unsigned short* wfc1t = (unsigned short*)(ws + 25165824);     // 294,912 B
    unsigned short* wfc2t = (unsigned short*)(ws + 25460736);     // 294,912 B
    unsigned short* wqkvt = (unsigned short*)(ws + 25755648);     // 221,184 B
    unsigned short* wprojt= (unsigned short*)(ws + 25976832);     // 73,728 B
    float*          biasfp= (float*)(ws + 26050560);              // 98,304 B
    float*          bnsc  = (float*)(ws + 26148864);              // 768 B
    float*          bnsh  = (float*)(ws + 26149632);              // 768 B
    float*          convwt= (float*)(ws + 26150400);              // 6,912 B
    float* out = (float*)d_out;
    int noff = in_sizes[5] / NHh;

    prep_kernel<<<205, 256, 0, stream>>>(
        fc1_w, fc2_w, qkv_w, proj_w, biases, noff, bidx,
        bn_g, bn_b, bn_m, bn_v, conv_w,
        wfc1t, wfc2t, wqkvt, wprojt, biasfp, bnsc, bnsh, convwt);

    size_t smem1 = 122368;
    hipFuncSetAttribute((const void*)attn_win_mfma,
                        hipFuncAttributeMaxDynamicSharedMemorySize, (int)smem1);
    attn_win_mfma<<<16*100, 512, smem1, stream>>>(
        x, ln1_w, ln1_b, wqkvt, qkv_b, biasfp, wprojt, proj_b, x2);

    size_t smem2 = 25600;
    conv_mlp4<<<65536/32, 256, smem2, stream>>>(
        x2, convwt, bnsc, bnsh, ln2_w, ln2_b,
        wfc1t, fc1_b, wfc2t, fc2_b, out);
}